// Round 1
// 466.542 us; speedup vs baseline: 1.0893x; 1.0893x over previous
//
#include <hip/hip_runtime.h>

#define NN 4
#define CC 256
#define HH 128
#define FWBv 16
#define BLK 8
#define NBBOX 100
#define MM (NBBOX * NN * FWBv * FWBv)  // 102400

typedef __attribute__((ext_vector_type(8))) short bf16x8;
typedef __attribute__((ext_vector_type(4))) float f32x4;

__device__ __forceinline__ unsigned short f2bf(float x) {
  union { float f; unsigned int u; } v; v.f = x;
  unsigned int r = v.u + 0x7FFFu + ((v.u >> 16) & 1u);
  return (unsigned short)(r >> 16);
}

// async global->LDS, 16B per lane; LDS dest = wave-uniform base + lane*16
__device__ __forceinline__ void async16(const void* g, void* l) {
  __builtin_amdgcn_global_load_lds(
      (__attribute__((address_space(1))) void*)(g),
      (__attribute__((address_space(3))) void*)(l), 16, 0, 0);
}

// ---------------- Kernel 0: weight fp32 -> bf16 ----------------
__global__ __launch_bounds__(256) void k_convert(
    const float* __restrict__ Wf, const float* __restrict__ Ww,
    const float* __restrict__ Wpw,
    unsigned short* __restrict__ oWf, unsigned short* __restrict__ oWw,
    unsigned short* __restrict__ oWpw) {
  int i = blockIdx.x * 256 + threadIdx.x;  // grid = 256 blocks -> i < 65536
  oWf[i] = f2bf(Wf[i]);
  oWw[i] = f2bf(Ww[i]);
  if (i < 64 * 256) oWpw[i] = f2bf(Wpw[i]);
}

// ---- k1 staging helpers (rule-21 swizzle: linear LDS dest via global_load_lds,
//      inverse-swizzled GLOBAL source, swizzled LDS read) ----

// Stage one BK=32 chunk of a [256 rows][256 k] bf16 weight into a 16KB buffer.
// Layout: row stride 64B = 4 x 16B slots; stored slot = s ^ ((row>>1)&3).
// Wave w stages rows [w*64, w*64+64) -- the SAME rows it later reads, so no
// cross-wave sync is needed for this buffer.
__device__ __forceinline__ void stage_w(const unsigned short* __restrict__ Wp,
                                        int kc, unsigned short* buf, int w,
                                        int lane) {
  const int srcs = ((lane & 3) ^ ((lane >> 3) & 3)) * 8;  // ushort offset
  const int rr = lane >> 2;                               // row within 16-row grp
#pragma unroll
  for (int i = 0; i < 4; ++i) {
    const int r0 = w * 64 + i * 16;  // wave-uniform
    async16(Wp + (size_t)(r0 + rr) * 256 + kc * 32 + srcs, buf + r0 * 32);
  }
}

// Stage one [64 rows][64 k] chunk (8KB) of Wpw. Row stride 128B = 8 slots;
// stored slot = s ^ (row&7). Wave w stages rows [w*16, w*16+16) == its own.
__device__ __forceinline__ void stage_wpw(const unsigned short* __restrict__ Wpw,
                                          unsigned short* buf, int kc4, int w,
                                          int lane) {
  const int srcs = ((lane & 7) ^ ((lane >> 3) & 7)) * 8;
  const int rr = lane >> 3;
#pragma unroll
  for (int i = 0; i < 2; ++i) {
    const int r0 = w * 16 + i * 8;  // wave-uniform
    async16(Wpw + (size_t)(r0 + rr) * 256 + kc4 * 64 + srcs, buf + r0 * 64);
  }
}

// One BK=32 compute step: 4x4 tile of 16x16x32 MFMA.
// Operand order mfma(Wfrag, xfrag): D.row(quad*4+reg) = output col offset,
// D.col(lane&15) = M row -> each lane owns 4 CONSECUTIVE output cols.
__device__ __forceinline__ void body16(const unsigned short* buf,
                                       const unsigned short (*xsp)[264],
                                       int kcol, int w, int lr, int quad,
                                       int wslot, f32x4 acc[4][4]) {
  bf16x8 aw[4], bx[4];
#pragma unroll
  for (int nt = 0; nt < 4; ++nt)
    aw[nt] = *(const bf16x8*)&buf[(w * 64 + nt * 16 + lr) * 32 + wslot];
#pragma unroll
  for (int mt = 0; mt < 4; ++mt)
    bx[mt] = *(const bf16x8*)&xsp[mt * 16 + lr][kcol];
#pragma unroll
  for (int mt = 0; mt < 4; ++mt)
#pragma unroll
    for (int nt = 0; nt < 4; ++nt)
      acc[mt][nt] = __builtin_amdgcn_mfma_f32_16x16x32_bf16(
          aw[nt], bx[mt], acc[mt][nt], 0, 0, 0);
}

// ---------------- Kernel 1: feat_f, feat_w, point_weight ----------------
// grid = MM/64 blocks, 256 threads (4 waves). Per-wave free-running depth-2
// staging pipeline (counted vmcnt, NO per-chunk barriers): each wave stages
// and consumes only its own 64 weight rows. Barriers only around the
// feat_w -> xs rewrite (cross-wave).
__global__ __launch_bounds__(256) void k1(
    const float* __restrict__ rois,
    const unsigned short* __restrict__ Wf,   // bf16 [256][256]
    const unsigned short* __restrict__ Ww,   // bf16 [256][256]
    const unsigned short* __restrict__ Wpw,  // bf16 [64][256]
    const float* __restrict__ bf_, const float* __restrict__ bw_,
    const float* __restrict__ bpw_,
    float* __restrict__ fused_slot,  // d_out[0 : M*256]   <- feat_f
    float* __restrict__ out_slot)    // d_out[M*256 : ]    <- pw in cols 0..63
{
  __shared__ __align__(16) unsigned short xs[64][264];  // 33.8 KB (pad: VALU-written, OK)
  __shared__ __align__(16) unsigned short bs[2][8192];  // 2 x 16 KB dbuf
  unsigned short* bsf = &bs[0][0];                      // 32 KB flat (pass C)
  const int t = threadIdx.x;
  const int lane = t & 63, w = t >> 6;
  const int lr = lane & 15, quad = lane >> 4;
  const int row_base = blockIdx.x * 64;
  const int wslot = (quad ^ ((lr >> 1) & 3)) << 3;  // swizzled 16B slot (ushorts)

  // prologue: issue Wf chunk 0 before the X stage so its latency hides there
  stage_w(Wf, 0, &bs[0][0], w, lane);

  // stage X: 64x256 fp32 -> bf16 LDS (coalesced float4 loads)
#pragma unroll
  for (int i = 0; i < 16; ++i) {
    const int elem = (i * 256 + t) * 4;
    const int r = elem >> 8, c = elem & 255;
    const float4 v = *(const float4*)(rois + (size_t)row_base * 256 + elem);
    unsigned int lo = f2bf(v.x) | ((unsigned int)f2bf(v.y) << 16);
    unsigned int hi = f2bf(v.z) | ((unsigned int)f2bf(v.w) << 16);
    *(uint2*)&xs[r][c] = make_uint2(lo, hi);
  }
  asm volatile("s_waitcnt vmcnt(0) lgkmcnt(0)" ::: "memory");
  __builtin_amdgcn_s_barrier();  // xs visible to all waves (chunk0 also done)

  f32x4 acc[4][4];
#pragma unroll
  for (int mt = 0; mt < 4; ++mt)
#pragma unroll
    for (int nt = 0; nt < 4; ++nt) acc[mt][nt] = (f32x4){0.f, 0.f, 0.f, 0.f};

  // ---- pass A: feat_f = relu(x @ Wf^T + bf) ----
#pragma unroll
  for (int kc = 0; kc < 8; ++kc) {
    if (kc < 7) stage_w(Wf, kc + 1, &bs[(kc + 1) & 1][0], w, lane);
    else        stage_w(Ww, 0, &bs[0][0], w, lane);  // prefetch pass B chunk 0
    // wait: everything except the 4 loads just issued is retired
    asm volatile("s_waitcnt vmcnt(4)" ::: "memory");
    body16(&bs[kc & 1][0], xs, kc * 32 + quad * 8, w, lr, quad, wslot, acc);
  }

  // epilogue A: vectorized float4 stores (lane owns 4 consecutive cols)
#pragma unroll
  for (int nt = 0; nt < 4; ++nt) {
    const int col0 = w * 64 + nt * 16 + quad * 4;
    const float4 b4 = *(const float4*)(bf_ + col0);
#pragma unroll
    for (int mt = 0; mt < 4; ++mt) {
      float4 v;
      v.x = acc[mt][nt][0] + b4.x; v.x = v.x > 0.f ? v.x : 0.f;
      v.y = acc[mt][nt][1] + b4.y; v.y = v.y > 0.f ? v.y : 0.f;
      v.z = acc[mt][nt][2] + b4.z; v.z = v.z > 0.f ? v.z : 0.f;
      v.w = acc[mt][nt][3] + b4.w; v.w = v.w > 0.f ? v.w : 0.f;
      *(float4*)(fused_slot + (size_t)(row_base + mt * 16 + lr) * 256 + col0) = v;
      acc[mt][nt] = (f32x4){0.f, 0.f, 0.f, 0.f};  // reset for pass B
    }
  }

  // ---- pass B: feat_w = relu(x @ Ww^T + bw) ----
#pragma unroll
  for (int kc = 0; kc < 8; ++kc) {
    if (kc < 7) {
      stage_w(Ww, kc + 1, &bs[(kc + 1) & 1][0], w, lane);
      asm volatile("s_waitcnt vmcnt(4)" ::: "memory");
    } else {
      asm volatile("s_waitcnt vmcnt(0)" ::: "memory");
    }
    body16(&bs[kc & 1][0], xs, kc * 32 + quad * 8, w, lr, quad, wslot, acc);
  }

  __builtin_amdgcn_s_barrier();  // ALL waves done reading xs and bs

  // stage all 4 Wpw chunks (4 x 8KB fills bs exactly; each wave its own rows)
#pragma unroll
  for (int c = 0; c < 4; ++c) stage_wpw(Wpw, bsf + c * 4096, c, w, lane);

  // epilogue B: feat_w = relu(acc + bias) -> bf16 back into xs (uint2 writes)
#pragma unroll
  for (int nt = 0; nt < 4; ++nt) {
    const int col0 = w * 64 + nt * 16 + quad * 4;
    const float4 b4 = *(const float4*)(bw_ + col0);
#pragma unroll
    for (int mt = 0; mt < 4; ++mt) {
      float v0 = acc[mt][nt][0] + b4.x; v0 = v0 > 0.f ? v0 : 0.f;
      float v1 = acc[mt][nt][1] + b4.y; v1 = v1 > 0.f ? v1 : 0.f;
      float v2 = acc[mt][nt][2] + b4.z; v2 = v2 > 0.f ? v2 : 0.f;
      float v3 = acc[mt][nt][3] + b4.w; v3 = v3 > 0.f ? v3 : 0.f;
      unsigned int lo = f2bf(v0) | ((unsigned int)f2bf(v1) << 16);
      unsigned int hi = f2bf(v2) | ((unsigned int)f2bf(v3) << 16);
      *(uint2*)&xs[mt * 16 + lr][col0] = make_uint2(lo, hi);
    }
  }
  asm volatile("s_waitcnt vmcnt(0) lgkmcnt(0)" ::: "memory");
  __builtin_amdgcn_s_barrier();  // new xs (feat_w) visible; Wpw staged

  // ---- pass C: pw = feat_w @ Wpw^T + bpw, wave w -> cols [w*16, w*16+16) ----
  f32x4 acc2[4];
#pragma unroll
  for (int mt = 0; mt < 4; ++mt) acc2[mt] = (f32x4){0.f, 0.f, 0.f, 0.f};
#pragma unroll
  for (int c = 0; c < 4; ++c) {
#pragma unroll
    for (int kt = 0; kt < 2; ++kt) {
      const int sl = ((kt * 4 + quad) ^ (lr & 7)) << 3;
      const bf16x8 apw =
          *(const bf16x8*)&bsf[c * 4096 + (w * 16 + lr) * 64 + sl];
      const int kcol = c * 64 + kt * 32 + quad * 8;
#pragma unroll
      for (int mt = 0; mt < 4; ++mt) {
        const bf16x8 bx = *(const bf16x8*)&xs[mt * 16 + lr][kcol];
        acc2[mt] =
            __builtin_amdgcn_mfma_f32_16x16x32_bf16(apw, bx, acc2[mt], 0, 0, 0);
      }
    }
  }
  // epilogue C: float4 stores, no relu
  {
    const int j0 = w * 16 + quad * 4;
    const float4 bj = *(const float4*)(bpw_ + j0);
#pragma unroll
    for (int mt = 0; mt < 4; ++mt) {
      float4 v;
      v.x = acc2[mt][0] + bj.x;
      v.y = acc2[mt][1] + bj.y;
      v.z = acc2[mt][2] + bj.z;
      v.w = acc2[mt][3] + bj.w;
      *(float4*)(out_slot + (size_t)(row_base + mt * 16 + lr) * 256 + j0) = v;
    }
  }
}

// ---------------- Kernel 2: einsum + fused add ----------------
// grid = 1024 blocks (one per (n,p,q)), 512 threads (8 waves).
// out[k,c] = sum_j pw[k,j] * fb[c,j];  fused = feat_f + out.
__global__ __launch_bounds__(512) void k2(
    const float* __restrict__ feature,
    float* __restrict__ fused_slot,  // holds feat_f on entry
    float* __restrict__ out_slot)    // holds pw in cols 0..63 on entry
{
  __shared__ unsigned short fbuf[256][72];  // fb[c][j] bf16
  __shared__ unsigned short pwb[112][72];   // pw[k][j] bf16, rows 100..111 zero
  const int t = threadIdx.x;
  const int lane = t & 63, w = t >> 6;
  const int lr = lane & 15, quad = lane >> 4;
  const int bid = blockIdx.x;               // base = (n*16+p)*16+q == bid
  const int n = bid >> 8, p = (bid >> 4) & 15, q = bid & 15;

  // zero pad rows k=100..111 (12 rows x 72 ushort = 432 uints), disjoint from loads
  if (t < 432) {
    const int r = 100 + t / 36, cw = t % 36;
    *(unsigned int*)&pwb[r][cw * 2] = 0u;
  }

  // stage feature block: (c,a) pairs, 8 contiguous floats each
  for (int pi = t; pi < 2048; pi += 512) {
    const int c = pi >> 3, a = pi & 7;
    const float* fp =
        feature + (((size_t)n * 256 + c) * 128 + p * 8 + a) * 128 + q * 8;
    const float4 v0 = *(const float4*)fp;
    const float4 v1 = *(const float4*)(fp + 4);
    unsigned int u0 = f2bf(v0.x) | ((unsigned int)f2bf(v0.y) << 16);
    unsigned int u1 = f2bf(v0.z) | ((unsigned int)f2bf(v0.w) << 16);
    unsigned int u2 = f2bf(v1.x) | ((unsigned int)f2bf(v1.y) << 16);
    unsigned int u3 = f2bf(v1.z) | ((unsigned int)f2bf(v1.w) << 16);
    *(uint4*)&fbuf[c][a * 8] = make_uint4(u0, u1, u2, u3);
  }

  // stage pw rows: k = 0..99, 64 fp32 each from out_slot cols 0..63
  for (int pi = t; pi < 1600; pi += 512) {
    const int k = pi >> 4, ch = pi & 15;
    const float4 v =
        *(const float4*)(out_slot + (size_t)(bid + k * 1024) * 256 + ch * 4);
    unsigned int lo = f2bf(v.x) | ((unsigned int)f2bf(v.y) << 16);
    unsigned int hi = f2bf(v.z) | ((unsigned int)f2bf(v.w) << 16);
    *(uint2*)&pwb[k][ch * 4] = make_uint2(lo, hi);
  }
  __syncthreads();

  // GEMM: (112 x 64) @ (64 x 256), wave w -> cols 32w..32w+31
  f32x4 acc[7][2];
#pragma unroll
  for (int mt = 0; mt < 7; ++mt)
#pragma unroll
    for (int nt = 0; nt < 2; ++nt) acc[mt][nt] = (f32x4){0.f, 0.f, 0.f, 0.f};
#pragma unroll
  for (int kt = 0; kt < 2; ++kt) {
    const int kk = kt * 32 + quad * 8;
    bf16x8 a[7], b[2];
#pragma unroll
    for (int mt = 0; mt < 7; ++mt)
      a[mt] = *(const bf16x8*)&pwb[mt * 16 + lr][kk];
#pragma unroll
    for (int nt = 0; nt < 2; ++nt)
      b[nt] = *(const bf16x8*)&fbuf[w * 32 + nt * 16 + lr][kk];
#pragma unroll
    for (int mt = 0; mt < 7; ++mt)
#pragma unroll
      for (int nt = 0; nt < 2; ++nt)
        acc[mt][nt] =
            __builtin_amdgcn_mfma_f32_16x16x32_bf16(a[mt], b[nt], acc[mt][nt], 0, 0, 0);
  }

  // epilogue: write out + fused (= feat_f + out)
#pragma unroll
  for (int mt = 0; mt < 7; ++mt) {
#pragma unroll
    for (int r = 0; r < 4; ++r) {
      const int k = mt * 16 + quad * 4 + r;
      if (k < 100) {
        const size_t rowoff = (size_t)(bid + k * 1024) * 256;
#pragma unroll
        for (int nt = 0; nt < 2; ++nt) {
          const int c = w * 32 + nt * 16 + lr;
          const float val = acc[mt][nt][r];
          out_slot[rowoff + c] = val;
          fused_slot[rowoff + c] = fused_slot[rowoff + c] + val;
        }
      }
    }
  }
}

extern "C" void kernel_launch(void* const* d_in, const int* in_sizes, int n_in,
                              void* d_out, int out_size, void* d_ws, size_t ws_size,
                              hipStream_t stream) {
  const float* feature = (const float*)d_in[0];
  const float* rois = (const float*)d_in[1];
  const float* Ww = (const float*)d_in[2];
  const float* bw = (const float*)d_in[3];
  const float* Wf = (const float*)d_in[4];
  const float* bfv = (const float*)d_in[5];
  const float* Wpw = (const float*)d_in[6];
  const float* bpw = (const float*)d_in[7];

  unsigned short* wsWf = (unsigned short*)d_ws;       // 65536 bf16
  unsigned short* wsWw = wsWf + 256 * 256;            // 65536 bf16
  unsigned short* wsWpw = wsWw + 256 * 256;           // 16384 bf16  (total 288 KB)

  float* fused_slot = (float*)d_out;
  float* out_slot = fused_slot + (size_t)MM * 256;

  k_convert<<<256, 256, 0, stream>>>(Wf, Ww, Wpw, wsWf, wsWw, wsWpw);
  k1<<<MM / 64, 256, 0, stream>>>(rois, wsWf, wsWw, wsWpw, bfv, bw, bpw,
                                  fused_slot, out_slot);
  k2<<<NN * FWBv * FWBv, 512, 0, stream>>>(feature, fused_slot, out_slot);
}

// Round 2
// 455.752 us; speedup vs baseline: 1.1151x; 1.0237x over previous
//
#include <hip/hip_runtime.h>

#define NN 4
#define CC 256
#define HH 128
#define FWBv 16
#define BLK 8
#define NBBOX 100
#define MM (NBBOX * NN * FWBv * FWBv)  // 102400

typedef __attribute__((ext_vector_type(8))) short bf16x8;
typedef __attribute__((ext_vector_type(4))) float f32x4;

__device__ __forceinline__ unsigned short f2bf(float x) {
  union { float f; unsigned int u; } v; v.f = x;
  unsigned int r = v.u + 0x7FFFu + ((v.u >> 16) & 1u);
  return (unsigned short)(r >> 16);
}

__device__ __forceinline__ float bfbits2f(unsigned int hi16) {
  // hi16: bf16 payload already in the HIGH 16 bits
  union { float f; unsigned int u; } v; v.u = hi16;
  return v.f;
}

// async global->LDS, 16B per lane; LDS dest = wave-uniform base + lane*16
__device__ __forceinline__ void async16(const void* g, void* l) {
  __builtin_amdgcn_global_load_lds(
      (__attribute__((address_space(1))) void*)(g),
      (__attribute__((address_space(3))) void*)(l), 16, 0, 0);
}

// ---------------- Kernel 0: weight fp32 -> bf16 ----------------
__global__ __launch_bounds__(256) void k_convert(
    const float* __restrict__ Wf, const float* __restrict__ Ww,
    const float* __restrict__ Wpw,
    unsigned short* __restrict__ oWf, unsigned short* __restrict__ oWw,
    unsigned short* __restrict__ oWpw) {
  int i = blockIdx.x * 256 + threadIdx.x;  // grid = 256 blocks -> i < 65536
  oWf[i] = f2bf(Wf[i]);
  oWw[i] = f2bf(Ww[i]);
  if (i < 64 * 256) oWpw[i] = f2bf(Wpw[i]);
}

// ---- k1 staging helpers (rule-21 swizzle: linear LDS dest via global_load_lds,
//      inverse-swizzled GLOBAL source, swizzled LDS read) ----

// Stage one BK=32 chunk of a [256 rows][256 k] bf16 weight into a 16KB buffer.
// Row stride 64B = 4 x 16B slots; stored slot = s ^ ((row>>1)&3).
// Wave w stages rows [w*64, w*64+64) -- the SAME rows it later reads.
__device__ __forceinline__ void stage_w(const unsigned short* __restrict__ Wp,
                                        int kc, unsigned short* buf, int w,
                                        int lane) {
  const int srcs = ((lane & 3) ^ ((lane >> 3) & 3)) * 8;  // ushort offset
  const int rr = lane >> 2;                               // row within 16-row grp
#pragma unroll
  for (int i = 0; i < 4; ++i) {
    const int r0 = w * 64 + i * 16;  // wave-uniform
    async16(Wp + (size_t)(r0 + rr) * 256 + kc * 32 + srcs, buf + r0 * 32);
  }
}

// Stage one [64 rows][64 k] chunk (8KB) of Wpw. Row stride 128B = 8 slots;
// stored slot = s ^ (row&7). Wave w stages rows [w*16, w*16+16) == its own.
__device__ __forceinline__ void stage_wpw(const unsigned short* __restrict__ Wpw,
                                          unsigned short* buf, int kc4, int w,
                                          int lane) {
  const int srcs = ((lane & 7) ^ ((lane >> 3) & 7)) * 8;
  const int rr = lane >> 3;
#pragma unroll
  for (int i = 0; i < 2; ++i) {
    const int r0 = w * 16 + i * 8;  // wave-uniform
    async16(Wpw + (size_t)(r0 + rr) * 256 + kc4 * 64 + srcs, buf + r0 * 64);
  }
}

// One BK=32 compute step: 4x4 tile of 16x16x32 MFMA.
// Operand order mfma(Wfrag, xfrag): D.row(quad*4+reg) = output col offset,
// D.col(lane&15) = M row -> each lane owns 4 CONSECUTIVE output cols.
__device__ __forceinline__ void body16(const unsigned short* buf,
                                       const unsigned short (*xsp)[264],
                                       int kcol, int w, int lr, int quad,
                                       int wslot, f32x4 acc[4][4]) {
  bf16x8 aw[4], bx[4];
#pragma unroll
  for (int nt = 0; nt < 4; ++nt)
    aw[nt] = *(const bf16x8*)&buf[(w * 64 + nt * 16 + lr) * 32 + wslot];
#pragma unroll
  for (int mt = 0; mt < 4; ++mt)
    bx[mt] = *(const bf16x8*)&xsp[mt * 16 + lr][kcol];
  __builtin_amdgcn_s_setprio(1);
#pragma unroll
  for (int mt = 0; mt < 4; ++mt)
#pragma unroll
    for (int nt = 0; nt < 4; ++nt)
      acc[mt][nt] = __builtin_amdgcn_mfma_f32_16x16x32_bf16(
          aw[nt], bx[mt], acc[mt][nt], 0, 0, 0);
  __builtin_amdgcn_s_setprio(0);
}

// ---------------- Kernel 1: feat_f, feat_w, point_weight ----------------
// grid = MM/64 blocks, 256 threads (4 waves). Per-wave free-running depth-2
// staging pipeline (counted vmcnt, NO per-chunk barriers).
// Outputs packed bf16 into out_slot rows (1KB each):
//   bytes [0,128)   : pw bf16[64]      (pass C)
//   bytes [256,768) : feat_f bf16[256] (pass A)
// k2 reads both and overwrites the rows with final fp32 out.
__global__ __launch_bounds__(256) void k1(
    const float* __restrict__ rois,
    const unsigned short* __restrict__ Wf,   // bf16 [256][256]
    const unsigned short* __restrict__ Ww,   // bf16 [256][256]
    const unsigned short* __restrict__ Wpw,  // bf16 [64][256]
    const float* __restrict__ bf_, const float* __restrict__ bw_,
    const float* __restrict__ bpw_,
    float* __restrict__ out_slot)
{
  __shared__ __align__(16) unsigned short xs[64][264];  // 33.8 KB
  __shared__ __align__(16) unsigned short bs[2][8192];  // 2 x 16 KB dbuf
  unsigned short* bsf = &bs[0][0];                      // 32 KB flat (pass C)
  unsigned short* os = (unsigned short*)out_slot;
  const int t = threadIdx.x;
  const int lane = t & 63, w = t >> 6;
  const int lr = lane & 15, quad = lane >> 4;
  const int row_base = blockIdx.x * 64;
  const int wslot = (quad ^ ((lr >> 1) & 3)) << 3;  // swizzled 16B slot (ushorts)

  // prologue: issue Wf chunk 0 before the X stage so its latency hides there
  stage_w(Wf, 0, &bs[0][0], w, lane);

  // stage X: 64x256 fp32 -> bf16 LDS (coalesced float4 loads)
#pragma unroll
  for (int i = 0; i < 16; ++i) {
    const int elem = (i * 256 + t) * 4;
    const int r = elem >> 8, c = elem & 255;
    const float4 v = *(const float4*)(rois + (size_t)row_base * 256 + elem);
    unsigned int lo = f2bf(v.x) | ((unsigned int)f2bf(v.y) << 16);
    unsigned int hi = f2bf(v.z) | ((unsigned int)f2bf(v.w) << 16);
    *(uint2*)&xs[r][c] = make_uint2(lo, hi);
  }
  asm volatile("s_waitcnt vmcnt(0) lgkmcnt(0)" ::: "memory");
  __builtin_amdgcn_s_barrier();  // xs visible to all waves (chunk0 also done)

  f32x4 acc[4][4];
#pragma unroll
  for (int mt = 0; mt < 4; ++mt)
#pragma unroll
    for (int nt = 0; nt < 4; ++nt) acc[mt][nt] = (f32x4){0.f, 0.f, 0.f, 0.f};

  // ---- pass A: feat_f = relu(x @ Wf^T + bf) ----
#pragma unroll
  for (int kc = 0; kc < 8; ++kc) {
    if (kc < 7) stage_w(Wf, kc + 1, &bs[(kc + 1) & 1][0], w, lane);
    else        stage_w(Ww, 0, &bs[0][0], w, lane);  // prefetch pass B chunk 0
    asm volatile("s_waitcnt vmcnt(4)" ::: "memory");
    body16(&bs[kc & 1][0], xs, kc * 32 + quad * 8, w, lr, quad, wslot, acc);
  }

  // epilogue A: feat_f = relu(acc+bias) -> bf16 into out_slot bytes [256,768)
#pragma unroll
  for (int nt = 0; nt < 4; ++nt) {
    const int col0 = w * 64 + nt * 16 + quad * 4;
    const float4 b4 = *(const float4*)(bf_ + col0);
#pragma unroll
    for (int mt = 0; mt < 4; ++mt) {
      float v0 = acc[mt][nt][0] + b4.x; v0 = v0 > 0.f ? v0 : 0.f;
      float v1 = acc[mt][nt][1] + b4.y; v1 = v1 > 0.f ? v1 : 0.f;
      float v2 = acc[mt][nt][2] + b4.z; v2 = v2 > 0.f ? v2 : 0.f;
      float v3 = acc[mt][nt][3] + b4.w; v3 = v3 > 0.f ? v3 : 0.f;
      unsigned int lo = f2bf(v0) | ((unsigned int)f2bf(v1) << 16);
      unsigned int hi = f2bf(v2) | ((unsigned int)f2bf(v3) << 16);
      *(uint2*)&os[(size_t)(row_base + mt * 16 + lr) * 512 + 128 + col0] =
          make_uint2(lo, hi);
      acc[mt][nt] = (f32x4){0.f, 0.f, 0.f, 0.f};  // reset for pass B
    }
  }

  // ---- pass B: feat_w = relu(x @ Ww^T + bw) ----
#pragma unroll
  for (int kc = 0; kc < 8; ++kc) {
    if (kc < 7) {
      stage_w(Ww, kc + 1, &bs[(kc + 1) & 1][0], w, lane);
      asm volatile("s_waitcnt vmcnt(4)" ::: "memory");
    } else {
      asm volatile("s_waitcnt vmcnt(0)" ::: "memory");
    }
    body16(&bs[kc & 1][0], xs, kc * 32 + quad * 8, w, lr, quad, wslot, acc);
  }

  __builtin_amdgcn_s_barrier();  // ALL waves done reading xs and bs

  // stage all 4 Wpw chunks (4 x 8KB fills bs exactly; each wave its own rows)
#pragma unroll
  for (int c = 0; c < 4; ++c) stage_wpw(Wpw, bsf + c * 4096, c, w, lane);

  // epilogue B: feat_w = relu(acc + bias) -> bf16 back into xs (uint2 writes)
#pragma unroll
  for (int nt = 0; nt < 4; ++nt) {
    const int col0 = w * 64 + nt * 16 + quad * 4;
    const float4 b4 = *(const float4*)(bw_ + col0);
#pragma unroll
    for (int mt = 0; mt < 4; ++mt) {
      float v0 = acc[mt][nt][0] + b4.x; v0 = v0 > 0.f ? v0 : 0.f;
      float v1 = acc[mt][nt][1] + b4.y; v1 = v1 > 0.f ? v1 : 0.f;
      float v2 = acc[mt][nt][2] + b4.z; v2 = v2 > 0.f ? v2 : 0.f;
      float v3 = acc[mt][nt][3] + b4.w; v3 = v3 > 0.f ? v3 : 0.f;
      unsigned int lo = f2bf(v0) | ((unsigned int)f2bf(v1) << 16);
      unsigned int hi = f2bf(v2) | ((unsigned int)f2bf(v3) << 16);
      *(uint2*)&xs[mt * 16 + lr][col0] = make_uint2(lo, hi);
    }
  }
  asm volatile("s_waitcnt vmcnt(0) lgkmcnt(0)" ::: "memory");
  __builtin_amdgcn_s_barrier();  // new xs (feat_w) visible; Wpw staged

  // ---- pass C: pw = feat_w @ Wpw^T + bpw, wave w -> cols [w*16, w*16+16) ----
  f32x4 acc2[4];
#pragma unroll
  for (int mt = 0; mt < 4; ++mt) acc2[mt] = (f32x4){0.f, 0.f, 0.f, 0.f};
#pragma unroll
  for (int c = 0; c < 4; ++c) {
#pragma unroll
    for (int kt = 0; kt < 2; ++kt) {
      const int sl = ((kt * 4 + quad) ^ (lr & 7)) << 3;
      const bf16x8 apw =
          *(const bf16x8*)&bsf[c * 4096 + (w * 16 + lr) * 64 + sl];
      const int kcol = c * 64 + kt * 32 + quad * 8;
      __builtin_amdgcn_s_setprio(1);
#pragma unroll
      for (int mt = 0; mt < 4; ++mt) {
        const bf16x8 bx = *(const bf16x8*)&xs[mt * 16 + lr][kcol];
        acc2[mt] =
            __builtin_amdgcn_mfma_f32_16x16x32_bf16(apw, bx, acc2[mt], 0, 0, 0);
      }
      __builtin_amdgcn_s_setprio(0);
    }
  }
  // epilogue C: pw bf16 into out_slot bytes [0,128)
  {
    const int j0 = w * 16 + quad * 4;
    const float4 bj = *(const float4*)(bpw_ + j0);
#pragma unroll
    for (int mt = 0; mt < 4; ++mt) {
      float v0 = acc2[mt][0] + bj.x;
      float v1 = acc2[mt][1] + bj.y;
      float v2 = acc2[mt][2] + bj.z;
      float v3 = acc2[mt][3] + bj.w;
      unsigned int lo = f2bf(v0) | ((unsigned int)f2bf(v1) << 16);
      unsigned int hi = f2bf(v2) | ((unsigned int)f2bf(v3) << 16);
      *(uint2*)&os[(size_t)(row_base + mt * 16 + lr) * 512 + j0] =
          make_uint2(lo, hi);
    }
  }
}

// ---------------- Kernel 2: einsum + fused add ----------------
// grid = 1024 blocks (one per (n,p,q)), 512 threads (8 waves).
// out[k,c] = sum_j pw[k,j] * fb[c,j];  fused = feat_f + out.
// pw / feat_f arrive as bf16 packed in out_slot rows (see k1).
// MFMA operand order mfma(fb, pw): lane owns 4 consecutive channels -> float4
// stores. One vmcnt(0)+barrier fences feat_f reads vs row overwrites.
__global__ __launch_bounds__(512) void k2(
    const float* __restrict__ feature,
    float* __restrict__ fused_slot,
    float* __restrict__ out_slot)
{
  __shared__ unsigned short fbuf[256][72];  // fb[c][j] bf16
  __shared__ unsigned short pwb[112][72];   // pw[k][j] bf16, rows 100..111 zero
  const int t = threadIdx.x;
  const int lane = t & 63, w = t >> 6;
  const int lr = lane & 15, quad = lane >> 4;
  const int bid = blockIdx.x;               // base = (n*16+p)*16+q == bid
  const int n = bid >> 8, p = (bid >> 4) & 15, q = bid & 15;
  const unsigned short* os = (const unsigned short*)out_slot;

  // zero pad rows k=100..111 (12 rows x 72 ushort = 432 uints)
  if (t < 432) {
    const int r = 100 + t / 36, cw = t % 36;
    *(unsigned int*)&pwb[r][cw * 2] = 0u;
  }

  // stage feature block: (c,a) pairs, 8 contiguous floats each
  for (int pi = t; pi < 2048; pi += 512) {
    const int c = pi >> 3, a = pi & 7;
    const float* fp =
        feature + (((size_t)n * 256 + c) * 128 + p * 8 + a) * 128 + q * 8;
    const float4 v0 = *(const float4*)fp;
    const float4 v1 = *(const float4*)(fp + 4);
    unsigned int u0 = f2bf(v0.x) | ((unsigned int)f2bf(v0.y) << 16);
    unsigned int u1 = f2bf(v0.z) | ((unsigned int)f2bf(v0.w) << 16);
    unsigned int u2 = f2bf(v1.x) | ((unsigned int)f2bf(v1.y) << 16);
    unsigned int u3 = f2bf(v1.z) | ((unsigned int)f2bf(v1.w) << 16);
    *(uint4*)&fbuf[c][a * 8] = make_uint4(u0, u1, u2, u3);
  }

  // stage pw rows (already bf16): k = 0..99, 128B per row
  for (int pi = t; pi < 1600; pi += 512) {
    const int k = pi >> 4, ch = pi & 15;
    const uint2 v = *(const uint2*)&os[(size_t)(bid + k * 1024) * 512 + ch * 4];
    *(uint2*)&pwb[k][ch * 4] = v;
  }
  __syncthreads();

  // prefetch feat_f bf16 (uint2 = 4 channels) for all our outputs
  uint2 ffp[7][2];
#pragma unroll
  for (int kt = 0; kt < 7; ++kt) {
    const int k = kt * 16 + lr;
    if (k < 100) {
      const size_t ro = (size_t)(bid + k * 1024) * 512;
#pragma unroll
      for (int ct = 0; ct < 2; ++ct) {
        const int c0 = w * 32 + ct * 16 + quad * 4;
        ffp[kt][ct] = *(const uint2*)&os[ro + 128 + c0];
      }
    }
  }

  // GEMM: mfma(fb_frag, pw_frag) -> D.row = channel, D.col = k
  f32x4 acc[7][2];
#pragma unroll
  for (int kt = 0; kt < 7; ++kt)
#pragma unroll
    for (int ct = 0; ct < 2; ++ct) acc[kt][ct] = (f32x4){0.f, 0.f, 0.f, 0.f};
#pragma unroll
  for (int kj = 0; kj < 2; ++kj) {
    const int kk = kj * 32 + quad * 8;
    bf16x8 pa[7], fa[2];
#pragma unroll
    for (int kt = 0; kt < 7; ++kt)
      pa[kt] = *(const bf16x8*)&pwb[kt * 16 + lr][kk];
#pragma unroll
    for (int ct = 0; ct < 2; ++ct)
      fa[ct] = *(const bf16x8*)&fbuf[w * 32 + ct * 16 + lr][kk];
    __builtin_amdgcn_s_setprio(1);
#pragma unroll
    for (int kt = 0; kt < 7; ++kt)
#pragma unroll
      for (int ct = 0; ct < 2; ++ct)
        acc[kt][ct] = __builtin_amdgcn_mfma_f32_16x16x32_bf16(
            fa[ct], pa[kt], acc[kt][ct], 0, 0, 0);
    __builtin_amdgcn_s_setprio(0);
  }

  // fence: all feat_f/pw reads of this block complete before any row overwrite
  asm volatile("s_waitcnt vmcnt(0)" ::: "memory");
  __builtin_amdgcn_s_barrier();

  // epilogue: float4 stores; k = kt*16+lr, channels c0..c0+3
#pragma unroll
  for (int kt = 0; kt < 7; ++kt) {
    const int k = kt * 16 + lr;
    if (k < 100) {
      const size_t ro = (size_t)(bid + k * 1024) * 256;
#pragma unroll
      for (int ct = 0; ct < 2; ++ct) {
        const int c0 = w * 32 + ct * 16 + quad * 4;
        float4 v;
        v.x = acc[kt][ct][0];
        v.y = acc[kt][ct][1];
        v.z = acc[kt][ct][2];
        v.w = acc[kt][ct][3];
        *(float4*)(out_slot + ro + c0) = v;
        const uint2 ff = ffp[kt][ct];
        float4 f;
        f.x = v.x + bfbits2f(ff.x << 16);
        f.y = v.y + bfbits2f(ff.x & 0xffff0000u);
        f.z = v.z + bfbits2f(ff.y << 16);
        f.w = v.w + bfbits2f(ff.y & 0xffff0000u);
        *(float4*)(fused_slot + ro + c0) = f;
      }
    }
  }
}

extern "C" void kernel_launch(void* const* d_in, const int* in_sizes, int n_in,
                              void* d_out, int out_size, void* d_ws, size_t ws_size,
                              hipStream_t stream) {
  const float* feature = (const float*)d_in[0];
  const float* rois = (const float*)d_in[1];
  const float* Ww = (const float*)d_in[2];
  const float* bw = (const float*)d_in[3];
  const float* Wf = (const float*)d_in[4];
  const float* bfv = (const float*)d_in[5];
  const float* Wpw = (const float*)d_in[6];
  const float* bpw = (const float*)d_in[7];

  unsigned short* wsWf = (unsigned short*)d_ws;       // 65536 bf16
  unsigned short* wsWw = wsWf + 256 * 256;            // 65536 bf16
  unsigned short* wsWpw = wsWw + 256 * 256;           // 16384 bf16  (total 288 KB)

  float* fused_slot = (float*)d_out;
  float* out_slot = fused_slot + (size_t)MM * 256;

  k_convert<<<256, 256, 0, stream>>>(Wf, Ww, Wpw, wsWf, wsWw, wsWpw);
  k1<<<MM / 64, 256, 0, stream>>>(rois, wsWf, wsWw, wsWpw, bfv, bw, bpw,
                                  out_slot);
  k2<<<NN * FWBv * FWBv, 512, 0, stream>>>(feature, fused_slot, out_slot);
}

// Round 3
// 441.443 us; speedup vs baseline: 1.1512x; 1.0324x over previous
//
#include <hip/hip_runtime.h>

#define NN 4
#define CC 256
#define HH 128
#define FWBv 16
#define BLK 8
#define NBBOX 100
#define MM (NBBOX * NN * FWBv * FWBv)  // 102400

typedef __attribute__((ext_vector_type(8))) short bf16x8;
typedef __attribute__((ext_vector_type(4))) float f32x4;

__device__ __forceinline__ unsigned short f2bf(float x) {
  union { float f; unsigned int u; } v; v.f = x;
  unsigned int r = v.u + 0x7FFFu + ((v.u >> 16) & 1u);
  return (unsigned short)(r >> 16);
}

__device__ __forceinline__ float bfbits2f(unsigned int hi16) {
  union { float f; unsigned int u; } v; v.u = hi16;
  return v.f;
}

__device__ __forceinline__ unsigned int pk(float a, float b) {
  return (unsigned int)f2bf(a) | ((unsigned int)f2bf(b) << 16);
}

// ---------------- Kernel 0: weight fp32 -> bf16, FRAGMENT-MAJOR ----------------
// Wf/Ww: fragment f = (kc*16 + g)*64 + lane  (kc<8, g<16, lane<64)
//   holds W[g*16 + (lane&15)][kc*32 + (lane>>4)*8 + j], j=0..7  (16B per lane)
// Wpw:   fragment f = (kc*4 + g)*64 + lane   (kc<8, g<4)
// A wave's MFMA A-operand load is then ONE fully-coalesced 1KB dwordx4 load.
__global__ __launch_bounds__(256) void k_convert(
    const float* __restrict__ Wf, const float* __restrict__ Ww,
    const float* __restrict__ Wpw,
    unsigned short* __restrict__ oWf, unsigned short* __restrict__ oWw,
    unsigned short* __restrict__ oWpw) {
  const int i = blockIdx.x * 256 + threadIdx.x;  // grid = 40 blocks -> i < 10240
  if (i < 8192) {
    const int lane = i & 63, g = (i >> 6) & 15, kc = i >> 10;
    const int row = g * 16 + (lane & 15);
    const int col0 = kc * 32 + (lane >> 4) * 8;
    {
      const float* s = Wf + (size_t)row * 256 + col0;
      const float4 a = *(const float4*)s, b = *(const float4*)(s + 4);
      *(uint4*)(oWf + (size_t)i * 8) =
          make_uint4(pk(a.x, a.y), pk(a.z, a.w), pk(b.x, b.y), pk(b.z, b.w));
    }
    {
      const float* s = Ww + (size_t)row * 256 + col0;
      const float4 a = *(const float4*)s, b = *(const float4*)(s + 4);
      *(uint4*)(oWw + (size_t)i * 8) =
          make_uint4(pk(a.x, a.y), pk(a.z, a.w), pk(b.x, b.y), pk(b.z, b.w));
    }
  } else {
    const int j = i - 8192;  // [0, 2048)
    const int lane = j & 63, g = (j >> 6) & 3, kc = j >> 8;
    const int row = g * 16 + (lane & 15);
    const int col0 = kc * 32 + (lane >> 4) * 8;
    const float* s = Wpw + (size_t)row * 256 + col0;
    const float4 a = *(const float4*)s, b = *(const float4*)(s + 4);
    *(uint4*)(oWpw + (size_t)j * 8) =
        make_uint4(pk(a.x, a.y), pk(a.z, a.w), pk(b.x, b.y), pk(b.z, b.w));
  }
}

// fragment load: one coalesced 1KB global_load_dwordx4 per wave
__device__ __forceinline__ bf16x8 ld_frag(const unsigned short* __restrict__ W,
                                          int frag, int lane) {
  return *(const bf16x8*)(W + (((size_t)frag * 64 + lane) << 3));
}

// One BK=32 compute step: weights already in regs; 4 ds_read (xs) + 16 MFMA.
// Operand order mfma(Wfrag, xfrag): lane owns 4 CONSECUTIVE output cols.
__device__ __forceinline__ void bodyR(const bf16x8 aw[4],
                                      const unsigned short (*xsp)[264],
                                      int kcol, int lr, f32x4 acc[4][4]) {
  bf16x8 bx[4];
#pragma unroll
  for (int mt = 0; mt < 4; ++mt)
    bx[mt] = *(const bf16x8*)&xsp[mt * 16 + lr][kcol];
  __builtin_amdgcn_s_setprio(1);
#pragma unroll
  for (int mt = 0; mt < 4; ++mt)
#pragma unroll
    for (int nt = 0; nt < 4; ++nt)
      acc[mt][nt] = __builtin_amdgcn_mfma_f32_16x16x32_bf16(
          aw[nt], bx[mt], acc[mt][nt], 0, 0, 0);
  __builtin_amdgcn_s_setprio(0);
}

// ---------------- Kernel 1: feat_f, feat_w, point_weight ----------------
// grid = MM/64 blocks, 256 threads (4 waves), 3 blocks/CU (LDS 33.8KB,
// VGPR capped by __launch_bounds__(256,3)). Weights are consumed directly
// from L2 via fragment-major coalesced reg loads (no LDS staging, no bs,
// no per-chunk sync). Only 3 barriers per block (x-tile + feat_w rewrite).
// Outputs packed bf16 into out_slot rows (1KB each):
//   bytes [0,128)   : pw bf16[64]      (pass C)
//   bytes [256,768) : feat_f bf16[256] (pass A)
__global__ __launch_bounds__(256, 3) void k1(
    const float* __restrict__ rois,
    const unsigned short* __restrict__ Wf,   // bf16 fragment-major [8192][8]
    const unsigned short* __restrict__ Ww,   // bf16 fragment-major [8192][8]
    const unsigned short* __restrict__ Wpw,  // bf16 fragment-major [2048][8]
    const float* __restrict__ bf_, const float* __restrict__ bw_,
    const float* __restrict__ bpw_,
    float* __restrict__ out_slot)
{
  __shared__ __align__(16) unsigned short xs[64][264];  // 33.8 KB, only LDS
  unsigned short* os = (unsigned short*)out_slot;
  const int t = threadIdx.x;
  const int lane = t & 63, w = t >> 6;
  const int lr = lane & 15, quad = lane >> 4;
  const int row_base = blockIdx.x * 64;
  const int w4 = w * 4;

  // preload pass-A chunk 0 weights (in flight during the X stage)
  bf16x8 aw[2][4];
#pragma unroll
  for (int nt = 0; nt < 4; ++nt) aw[0][nt] = ld_frag(Wf, w4 + nt, lane);

  // stage X: 64x256 fp32 -> bf16 LDS (coalesced float4 loads)
#pragma unroll
  for (int i = 0; i < 16; ++i) {
    const int elem = (i * 256 + t) * 4;
    const int r = elem >> 8, c = elem & 255;
    const float4 v = *(const float4*)(rois + (size_t)row_base * 256 + elem);
    *(uint2*)&xs[r][c] = make_uint2(pk(v.x, v.y), pk(v.z, v.w));
  }
  asm volatile("s_waitcnt lgkmcnt(0)" ::: "memory");
  __builtin_amdgcn_s_barrier();  // xs visible to all waves

  f32x4 acc[4][4];
#pragma unroll
  for (int mt = 0; mt < 4; ++mt)
#pragma unroll
    for (int nt = 0; nt < 4; ++nt) acc[mt][nt] = (f32x4){0.f, 0.f, 0.f, 0.f};

  // ---- pass A: feat_f = relu(x @ Wf^T + bf) ----
#pragma unroll
  for (int kc = 0; kc < 8; ++kc) {
    const unsigned short* nsrc = (kc < 7) ? Wf : Ww;  // tail prefetches pass B
    const int nkc = (kc < 7) ? kc + 1 : 0;
#pragma unroll
    for (int nt = 0; nt < 4; ++nt)
      aw[(kc + 1) & 1][nt] = ld_frag(nsrc, nkc * 16 + w4 + nt, lane);
    bodyR(aw[kc & 1], xs, kc * 32 + quad * 8, lr, acc);
  }

  // epilogue A: feat_f = relu(acc+bias) -> bf16 into out_slot bytes [256,768)
#pragma unroll
  for (int nt = 0; nt < 4; ++nt) {
    const int col0 = w * 64 + nt * 16 + quad * 4;
    const float4 b4 = *(const float4*)(bf_ + col0);
#pragma unroll
    for (int mt = 0; mt < 4; ++mt) {
      float v0 = acc[mt][nt][0] + b4.x; v0 = v0 > 0.f ? v0 : 0.f;
      float v1 = acc[mt][nt][1] + b4.y; v1 = v1 > 0.f ? v1 : 0.f;
      float v2 = acc[mt][nt][2] + b4.z; v2 = v2 > 0.f ? v2 : 0.f;
      float v3 = acc[mt][nt][3] + b4.w; v3 = v3 > 0.f ? v3 : 0.f;
      *(uint2*)&os[(size_t)(row_base + mt * 16 + lr) * 512 + 128 + col0] =
          make_uint2(pk(v0, v1), pk(v2, v3));
      acc[mt][nt] = (f32x4){0.f, 0.f, 0.f, 0.f};  // reset for pass B
    }
  }

  // ---- pass B: feat_w = relu(x @ Ww^T + bw) ----
#pragma unroll
  for (int kc = 0; kc < 8; ++kc) {
    if (kc < 7) {
#pragma unroll
      for (int nt = 0; nt < 4; ++nt)
        aw[(kc + 1) & 1][nt] = ld_frag(Ww, (kc + 1) * 16 + w4 + nt, lane);
    }
    bodyR(aw[kc & 1], xs, kc * 32 + quad * 8, lr, acc);
  }

  // prefetch ALL pass-C weights to regs (8KB/wave from L2, hides under epiB)
  bf16x8 apw[8];
#pragma unroll
  for (int idx = 0; idx < 8; ++idx)
    apw[idx] = ld_frag(Wpw, idx * 4 + w, lane);

  __builtin_amdgcn_s_barrier();  // ALL waves done reading xs (pass B)

  // epilogue B: feat_w = relu(acc + bias) -> bf16 back into xs
#pragma unroll
  for (int nt = 0; nt < 4; ++nt) {
    const int col0 = w * 64 + nt * 16 + quad * 4;
    const float4 b4 = *(const float4*)(bw_ + col0);
#pragma unroll
    for (int mt = 0; mt < 4; ++mt) {
      float v0 = acc[mt][nt][0] + b4.x; v0 = v0 > 0.f ? v0 : 0.f;
      float v1 = acc[mt][nt][1] + b4.y; v1 = v1 > 0.f ? v1 : 0.f;
      float v2 = acc[mt][nt][2] + b4.z; v2 = v2 > 0.f ? v2 : 0.f;
      float v3 = acc[mt][nt][3] + b4.w; v3 = v3 > 0.f ? v3 : 0.f;
      *(uint2*)&xs[mt * 16 + lr][col0] = make_uint2(pk(v0, v1), pk(v2, v3));
    }
  }
  asm volatile("s_waitcnt lgkmcnt(0)" ::: "memory");
  __builtin_amdgcn_s_barrier();  // new xs (feat_w) visible

  // ---- pass C: pw = feat_w @ Wpw^T + bpw, wave w -> cols [w*16, w*16+16) ----
  f32x4 acc2[4];
#pragma unroll
  for (int mt = 0; mt < 4; ++mt) acc2[mt] = (f32x4){0.f, 0.f, 0.f, 0.f};
#pragma unroll
  for (int idx = 0; idx < 8; ++idx) {  // idx = c*2+kt
    const int kcol = idx * 32 + quad * 8;
    __builtin_amdgcn_s_setprio(1);
#pragma unroll
    for (int mt = 0; mt < 4; ++mt) {
      const bf16x8 bx = *(const bf16x8*)&xs[mt * 16 + lr][kcol];
      acc2[mt] =
          __builtin_amdgcn_mfma_f32_16x16x32_bf16(apw[idx], bx, acc2[mt], 0, 0, 0);
    }
    __builtin_amdgcn_s_setprio(0);
  }
  // epilogue C: pw bf16 into out_slot bytes [0,128)
  {
    const int j0 = w * 16 + quad * 4;
    const float4 bj = *(const float4*)(bpw_ + j0);
#pragma unroll
    for (int mt = 0; mt < 4; ++mt) {
      const float v0 = acc2[mt][0] + bj.x, v1 = acc2[mt][1] + bj.y;
      const float v2 = acc2[mt][2] + bj.z, v3 = acc2[mt][3] + bj.w;
      *(uint2*)&os[(size_t)(row_base + mt * 16 + lr) * 512 + j0] =
          make_uint2(pk(v0, v1), pk(v2, v3));
    }
  }
}

// ---------------- Kernel 2: einsum + fused add ----------------
// (unchanged from R2 for attribution)
__global__ __launch_bounds__(512) void k2(
    const float* __restrict__ feature,
    float* __restrict__ fused_slot,
    float* __restrict__ out_slot)
{
  __shared__ unsigned short fbuf[256][72];  // fb[c][j] bf16
  __shared__ unsigned short pwb[112][72];   // pw[k][j] bf16, rows 100..111 zero
  const int t = threadIdx.x;
  const int lane = t & 63, w = t >> 6;
  const int lr = lane & 15, quad = lane >> 4;
  const int bid = blockIdx.x;               // base = (n*16+p)*16+q == bid
  const int n = bid >> 8, p = (bid >> 4) & 15, q = bid & 15;
  const unsigned short* os = (const unsigned short*)out_slot;

  // zero pad rows k=100..111 (12 rows x 72 ushort = 432 uints)
  if (t < 432) {
    const int r = 100 + t / 36, cw = t % 36;
    *(unsigned int*)&pwb[r][cw * 2] = 0u;
  }

  // stage feature block: (c,a) pairs, 8 contiguous floats each
  for (int pi = t; pi < 2048; pi += 512) {
    const int c = pi >> 3, a = pi & 7;
    const float* fp =
        feature + (((size_t)n * 256 + c) * 128 + p * 8 + a) * 128 + q * 8;
    const float4 v0 = *(const float4*)fp;
    const float4 v1 = *(const float4*)(fp + 4);
    *(uint4*)&fbuf[c][a * 8] =
        make_uint4(pk(v0.x, v0.y), pk(v0.z, v0.w), pk(v1.x, v1.y), pk(v1.z, v1.w));
  }

  // stage pw rows (already bf16): k = 0..99, 128B per row
  for (int pi = t; pi < 1600; pi += 512) {
    const int k = pi >> 4, ch = pi & 15;
    const uint2 v = *(const uint2*)&os[(size_t)(bid + k * 1024) * 512 + ch * 4];
    *(uint2*)&pwb[k][ch * 4] = v;
  }
  __syncthreads();

  // prefetch feat_f bf16 (uint2 = 4 channels) for all our outputs
  uint2 ffp[7][2];
#pragma unroll
  for (int kt = 0; kt < 7; ++kt) {
    const int k = kt * 16 + lr;
    if (k < 100) {
      const size_t ro = (size_t)(bid + k * 1024) * 512;
#pragma unroll
      for (int ct = 0; ct < 2; ++ct) {
        const int c0 = w * 32 + ct * 16 + quad * 4;
        ffp[kt][ct] = *(const uint2*)&os[ro + 128 + c0];
      }
    }
  }

  // GEMM: mfma(fb_frag, pw_frag) -> D.row = channel, D.col = k
  f32x4 acc[7][2];
#pragma unroll
  for (int kt = 0; kt < 7; ++kt)
#pragma unroll
    for (int ct = 0; ct < 2; ++ct) acc[kt][ct] = (f32x4){0.f, 0.f, 0.f, 0.f};
#pragma unroll
  for (int kj = 0; kj < 2; ++kj) {
    const int kk = kj * 32 + quad * 8;
    bf16x8 pa[7], fa[2];
#pragma unroll
    for (int kt = 0; kt < 7; ++kt)
      pa[kt] = *(const bf16x8*)&pwb[kt * 16 + lr][kk];
#pragma unroll
    for (int ct = 0; ct < 2; ++ct)
      fa[ct] = *(const bf16x8*)&fbuf[w * 32 + ct * 16 + lr][kk];
    __builtin_amdgcn_s_setprio(1);
#pragma unroll
    for (int kt = 0; kt < 7; ++kt)
#pragma unroll
      for (int ct = 0; ct < 2; ++ct)
        acc[kt][ct] = __builtin_amdgcn_mfma_f32_16x16x32_bf16(
            fa[ct], pa[kt], acc[kt][ct], 0, 0, 0);
    __builtin_amdgcn_s_setprio(0);
  }

  // fence: all feat_f/pw reads of this block complete before any row overwrite
  asm volatile("s_waitcnt vmcnt(0)" ::: "memory");
  __builtin_amdgcn_s_barrier();

  // epilogue: float4 stores; k = kt*16+lr, channels c0..c0+3
#pragma unroll
  for (int kt = 0; kt < 7; ++kt) {
    const int k = kt * 16 + lr;
    if (k < 100) {
      const size_t ro = (size_t)(bid + k * 1024) * 256;
#pragma unroll
      for (int ct = 0; ct < 2; ++ct) {
        const int c0 = w * 32 + ct * 16 + quad * 4;
        float4 v;
        v.x = acc[kt][ct][0];
        v.y = acc[kt][ct][1];
        v.z = acc[kt][ct][2];
        v.w = acc[kt][ct][3];
        *(float4*)(out_slot + ro + c0) = v;
        const uint2 ff = ffp[kt][ct];
        float4 f;
        f.x = v.x + bfbits2f(ff.x << 16);
        f.y = v.y + bfbits2f(ff.x & 0xffff0000u);
        f.z = v.z + bfbits2f(ff.y << 16);
        f.w = v.w + bfbits2f(ff.y & 0xffff0000u);
        *(float4*)(fused_slot + ro + c0) = f;
      }
    }
  }
}

extern "C" void kernel_launch(void* const* d_in, const int* in_sizes, int n_in,
                              void* d_out, int out_size, void* d_ws, size_t ws_size,
                              hipStream_t stream) {
  const float* feature = (const float*)d_in[0];
  const float* rois = (const float*)d_in[1];
  const float* Ww = (const float*)d_in[2];
  const float* bw = (const float*)d_in[3];
  const float* Wf = (const float*)d_in[4];
  const float* bfv = (const float*)d_in[5];
  const float* Wpw = (const float*)d_in[6];
  const float* bpw = (const float*)d_in[7];

  unsigned short* wsWf = (unsigned short*)d_ws;       // 65536 bf16 (frag-major)
  unsigned short* wsWw = wsWf + 256 * 256;            // 65536 bf16 (frag-major)
  unsigned short* wsWpw = wsWw + 256 * 256;           // 16384 bf16 (frag-major)

  float* fused_slot = (float*)d_out;
  float* out_slot = fused_slot + (size_t)MM * 256;

  k_convert<<<40, 256, 0, stream>>>(Wf, Ww, Wpw, wsWf, wsWw, wsWpw);
  k1<<<MM / 64, 256, 0, stream>>>(rois, wsWf, wsWw, wsWpw, bfv, bw, bpw,
                                  out_slot);
  k2<<<NN * FWBv * FWBv, 512, 0, stream>>>(feature, fused_slot, out_slot);
}

// Round 4
// 425.773 us; speedup vs baseline: 1.1936x; 1.0368x over previous
//
#include <hip/hip_runtime.h>

#define NN 4
#define CC 256
#define HH 128
#define FWBv 16
#define BLK 8
#define NBBOX 100
#define MM (NBBOX * NN * FWBv * FWBv)  // 102400

typedef __attribute__((ext_vector_type(8))) short bf16x8;
typedef __attribute__((ext_vector_type(4))) float f32x4;

__device__ __forceinline__ unsigned short f2bf(float x) {
  union { float f; unsigned int u; } v; v.f = x;
  unsigned int r = v.u + 0x7FFFu + ((v.u >> 16) & 1u);
  return (unsigned short)(r >> 16);
}

__device__ __forceinline__ float bfbits2f(unsigned int hi16) {
  union { float f; unsigned int u; } v; v.u = hi16;
  return v.f;
}

__device__ __forceinline__ unsigned int pk(float a, float b) {
  return (unsigned int)f2bf(a) | ((unsigned int)f2bf(b) << 16);
}

// ---------------- Kernel 0: weight fp32 -> bf16, FRAGMENT-MAJOR ----------------
// Wf/Ww: fragment f = (kc*16 + g)*64 + lane  (kc<8, g<16, lane<64)
//   holds W[g*16 + (lane&15)][kc*32 + (lane>>4)*8 + j], j=0..7  (16B per lane)
// Wpw:   fragment f = (kc*4 + g)*64 + lane   (kc<8, g<4)
// A wave's MFMA A-operand load is then ONE fully-coalesced 1KB dwordx4 load.
__global__ __launch_bounds__(256) void k_convert(
    const float* __restrict__ Wf, const float* __restrict__ Ww,
    const float* __restrict__ Wpw,
    unsigned short* __restrict__ oWf, unsigned short* __restrict__ oWw,
    unsigned short* __restrict__ oWpw) {
  const int i = blockIdx.x * 256 + threadIdx.x;  // grid = 40 blocks -> i < 10240
  if (i < 8192) {
    const int lane = i & 63, g = (i >> 6) & 15, kc = i >> 10;
    const int row = g * 16 + (lane & 15);
    const int col0 = kc * 32 + (lane >> 4) * 8;
    {
      const float* s = Wf + (size_t)row * 256 + col0;
      const float4 a = *(const float4*)s, b = *(const float4*)(s + 4);
      *(uint4*)(oWf + (size_t)i * 8) =
          make_uint4(pk(a.x, a.y), pk(a.z, a.w), pk(b.x, b.y), pk(b.z, b.w));
    }
    {
      const float* s = Ww + (size_t)row * 256 + col0;
      const float4 a = *(const float4*)s, b = *(const float4*)(s + 4);
      *(uint4*)(oWw + (size_t)i * 8) =
          make_uint4(pk(a.x, a.y), pk(a.z, a.w), pk(b.x, b.y), pk(b.z, b.w));
    }
  } else {
    const int j = i - 8192;  // [0, 2048)
    const int lane = j & 63, g = (j >> 6) & 3, kc = j >> 8;
    const int row = g * 16 + (lane & 15);
    const int col0 = kc * 32 + (lane >> 4) * 8;
    const float* s = Wpw + (size_t)row * 256 + col0;
    const float4 a = *(const float4*)s, b = *(const float4*)(s + 4);
    *(uint4*)(oWpw + (size_t)j * 8) =
        make_uint4(pk(a.x, a.y), pk(a.z, a.w), pk(b.x, b.y), pk(b.z, b.w));
  }
}

// fragment load: one coalesced 1KB global_load_dwordx4 per wave
__device__ __forceinline__ bf16x8 ld_frag(const unsigned short* __restrict__ W,
                                          int frag, int lane) {
  return *(const bf16x8*)(W + (((size_t)frag * 64 + lane) << 3));
}

// One BK=32 compute step: weights already in regs; 4 ds_read (xs) + 16 MFMA.
// Operand order mfma(Wfrag, xfrag): lane owns 4 CONSECUTIVE output cols.
__device__ __forceinline__ void bodyR(const bf16x8 aw[4],
                                      const unsigned short (*xsp)[264],
                                      int kcol, int lr, f32x4 acc[4][4]) {
  bf16x8 bx[4];
#pragma unroll
  for (int mt = 0; mt < 4; ++mt)
    bx[mt] = *(const bf16x8*)&xsp[mt * 16 + lr][kcol];
  __builtin_amdgcn_s_setprio(1);
#pragma unroll
  for (int mt = 0; mt < 4; ++mt)
#pragma unroll
    for (int nt = 0; nt < 4; ++nt)
      acc[mt][nt] = __builtin_amdgcn_mfma_f32_16x16x32_bf16(
          aw[nt], bx[mt], acc[mt][nt], 0, 0, 0);
  __builtin_amdgcn_s_setprio(0);
}

// ---------------- Kernel 1: feat_f, feat_w, point_weight ----------------
// (unchanged from R3)
__global__ __launch_bounds__(256, 3) void k1(
    const float* __restrict__ rois,
    const unsigned short* __restrict__ Wf,   // bf16 fragment-major [8192][8]
    const unsigned short* __restrict__ Ww,   // bf16 fragment-major [8192][8]
    const unsigned short* __restrict__ Wpw,  // bf16 fragment-major [2048][8]
    const float* __restrict__ bf_, const float* __restrict__ bw_,
    const float* __restrict__ bpw_,
    float* __restrict__ out_slot)
{
  __shared__ __align__(16) unsigned short xs[64][264];  // 33.8 KB, only LDS
  unsigned short* os = (unsigned short*)out_slot;
  const int t = threadIdx.x;
  const int lane = t & 63, w = t >> 6;
  const int lr = lane & 15, quad = lane >> 4;
  const int row_base = blockIdx.x * 64;
  const int w4 = w * 4;

  // preload pass-A chunk 0 weights (in flight during the X stage)
  bf16x8 aw[2][4];
#pragma unroll
  for (int nt = 0; nt < 4; ++nt) aw[0][nt] = ld_frag(Wf, w4 + nt, lane);

  // stage X: 64x256 fp32 -> bf16 LDS (coalesced float4 loads)
#pragma unroll
  for (int i = 0; i < 16; ++i) {
    const int elem = (i * 256 + t) * 4;
    const int r = elem >> 8, c = elem & 255;
    const float4 v = *(const float4*)(rois + (size_t)row_base * 256 + elem);
    *(uint2*)&xs[r][c] = make_uint2(pk(v.x, v.y), pk(v.z, v.w));
  }
  asm volatile("s_waitcnt lgkmcnt(0)" ::: "memory");
  __builtin_amdgcn_s_barrier();  // xs visible to all waves

  f32x4 acc[4][4];
#pragma unroll
  for (int mt = 0; mt < 4; ++mt)
#pragma unroll
    for (int nt = 0; nt < 4; ++nt) acc[mt][nt] = (f32x4){0.f, 0.f, 0.f, 0.f};

  // ---- pass A: feat_f = relu(x @ Wf^T + bf) ----
#pragma unroll
  for (int kc = 0; kc < 8; ++kc) {
    const unsigned short* nsrc = (kc < 7) ? Wf : Ww;  // tail prefetches pass B
    const int nkc = (kc < 7) ? kc + 1 : 0;
#pragma unroll
    for (int nt = 0; nt < 4; ++nt)
      aw[(kc + 1) & 1][nt] = ld_frag(nsrc, nkc * 16 + w4 + nt, lane);
    bodyR(aw[kc & 1], xs, kc * 32 + quad * 8, lr, acc);
  }

  // epilogue A: feat_f = relu(acc+bias) -> bf16 into out_slot bytes [256,768)
#pragma unroll
  for (int nt = 0; nt < 4; ++nt) {
    const int col0 = w * 64 + nt * 16 + quad * 4;
    const float4 b4 = *(const float4*)(bf_ + col0);
#pragma unroll
    for (int mt = 0; mt < 4; ++mt) {
      float v0 = acc[mt][nt][0] + b4.x; v0 = v0 > 0.f ? v0 : 0.f;
      float v1 = acc[mt][nt][1] + b4.y; v1 = v1 > 0.f ? v1 : 0.f;
      float v2 = acc[mt][nt][2] + b4.z; v2 = v2 > 0.f ? v2 : 0.f;
      float v3 = acc[mt][nt][3] + b4.w; v3 = v3 > 0.f ? v3 : 0.f;
      *(uint2*)&os[(size_t)(row_base + mt * 16 + lr) * 512 + 128 + col0] =
          make_uint2(pk(v0, v1), pk(v2, v3));
      acc[mt][nt] = (f32x4){0.f, 0.f, 0.f, 0.f};  // reset for pass B
    }
  }

  // ---- pass B: feat_w = relu(x @ Ww^T + bw) ----
#pragma unroll
  for (int kc = 0; kc < 8; ++kc) {
    if (kc < 7) {
#pragma unroll
      for (int nt = 0; nt < 4; ++nt)
        aw[(kc + 1) & 1][nt] = ld_frag(Ww, (kc + 1) * 16 + w4 + nt, lane);
    }
    bodyR(aw[kc & 1], xs, kc * 32 + quad * 8, lr, acc);
  }

  // prefetch ALL pass-C weights to regs (8KB/wave from L2, hides under epiB)
  bf16x8 apw[8];
#pragma unroll
  for (int idx = 0; idx < 8; ++idx)
    apw[idx] = ld_frag(Wpw, idx * 4 + w, lane);

  __builtin_amdgcn_s_barrier();  // ALL waves done reading xs (pass B)

  // epilogue B: feat_w = relu(acc + bias) -> bf16 back into xs
#pragma unroll
  for (int nt = 0; nt < 4; ++nt) {
    const int col0 = w * 64 + nt * 16 + quad * 4;
    const float4 b4 = *(const float4*)(bw_ + col0);
#pragma unroll
    for (int mt = 0; mt < 4; ++mt) {
      float v0 = acc[mt][nt][0] + b4.x; v0 = v0 > 0.f ? v0 : 0.f;
      float v1 = acc[mt][nt][1] + b4.y; v1 = v1 > 0.f ? v1 : 0.f;
      float v2 = acc[mt][nt][2] + b4.z; v2 = v2 > 0.f ? v2 : 0.f;
      float v3 = acc[mt][nt][3] + b4.w; v3 = v3 > 0.f ? v3 : 0.f;
      *(uint2*)&xs[mt * 16 + lr][col0] = make_uint2(pk(v0, v1), pk(v2, v3));
    }
  }
  asm volatile("s_waitcnt lgkmcnt(0)" ::: "memory");
  __builtin_amdgcn_s_barrier();  // new xs (feat_w) visible

  // ---- pass C: pw = feat_w @ Wpw^T + bpw, wave w -> cols [w*16, w*16+16) ----
  f32x4 acc2[4];
#pragma unroll
  for (int mt = 0; mt < 4; ++mt) acc2[mt] = (f32x4){0.f, 0.f, 0.f, 0.f};
#pragma unroll
  for (int idx = 0; idx < 8; ++idx) {  // idx = c*2+kt
    const int kcol = idx * 32 + quad * 8;
    __builtin_amdgcn_s_setprio(1);
#pragma unroll
    for (int mt = 0; mt < 4; ++mt) {
      const bf16x8 bx = *(const bf16x8*)&xs[mt * 16 + lr][kcol];
      acc2[mt] =
          __builtin_amdgcn_mfma_f32_16x16x32_bf16(apw[idx], bx, acc2[mt], 0, 0, 0);
    }
    __builtin_amdgcn_s_setprio(0);
  }
  // epilogue C: pw bf16 into out_slot bytes [0,128)
  {
    const int j0 = w * 16 + quad * 4;
    const float4 bj = *(const float4*)(bpw_ + j0);
#pragma unroll
    for (int mt = 0; mt < 4; ++mt) {
      const float v0 = acc2[mt][0] + bj.x, v1 = acc2[mt][1] + bj.y;
      const float v2 = acc2[mt][2] + bj.z, v3 = acc2[mt][3] + bj.w;
      *(uint2*)&os[(size_t)(row_base + mt * 16 + lr) * 512 + j0] =
          make_uint2(pk(v0, v1), pk(v2, v3));
    }
  }
}

// ---------------- Kernel 2: einsum + fused add ----------------
// grid = 1024 blocks, 512 threads (8 waves).
// NEW (R4): bijective chunked XCD swizzle. Blocks with consecutive logical bid
// share feature 128B cache lines (4 q-neighbors per line); the dispatcher
// round-robins hardware blockIdx across 8 non-coherent XCD L2s, so without
// remapping each line is fetched ~4x from HBM. Mapping d -> (d&7)*128 + d>>3
// gives XCD x the contiguous logical range [x*128, (x+1)*128), temporally
// adjacent -> each feature line fetched once per XCD.
__global__ __launch_bounds__(512) void k2(
    const float* __restrict__ feature,
    float* __restrict__ fused_slot,
    float* __restrict__ out_slot)
{
  __shared__ unsigned short fbuf[256][72];  // fb[c][j] bf16
  __shared__ unsigned short pwb[112][72];   // pw[k][j] bf16, rows 100..111 zero
  const int t = threadIdx.x;
  const int lane = t & 63, w = t >> 6;
  const int lr = lane & 15, quad = lane >> 4;
  const int d = blockIdx.x;                 // hardware block id
  const int bid = ((d & 7) << 7) | (d >> 3);  // XCD-chunked logical id
  const int n = bid >> 8, p = (bid >> 4) & 15, q = bid & 15;
  const unsigned short* os = (const unsigned short*)out_slot;

  // zero pad rows k=100..111 (12 rows x 72 ushort = 432 uints)
  if (t < 432) {
    const int r = 100 + t / 36, cw = t % 36;
    *(unsigned int*)&pwb[r][cw * 2] = 0u;
  }

  // stage feature block: (c,a) pairs, 8 contiguous floats each
  for (int pi = t; pi < 2048; pi += 512) {
    const int c = pi >> 3, a = pi & 7;
    const float* fp =
        feature + (((size_t)n * 256 + c) * 128 + p * 8 + a) * 128 + q * 8;
    const float4 v0 = *(const float4*)fp;
    const float4 v1 = *(const float4*)(fp + 4);
    *(uint4*)&fbuf[c][a * 8] =
        make_uint4(pk(v0.x, v0.y), pk(v0.z, v0.w), pk(v1.x, v1.y), pk(v1.z, v1.w));
  }

  // stage pw rows (already bf16): k = 0..99, 128B per row
  for (int pi = t; pi < 1600; pi += 512) {
    const int k = pi >> 4, ch = pi & 15;
    const uint2 v = *(const uint2*)&os[(size_t)(bid + k * 1024) * 512 + ch * 4];
    *(uint2*)&pwb[k][ch * 4] = v;
  }
  __syncthreads();

  // prefetch feat_f bf16 (uint2 = 4 channels) for all our outputs
  uint2 ffp[7][2];
#pragma unroll
  for (int kt = 0; kt < 7; ++kt) {
    const int k = kt * 16 + lr;
    if (k < 100) {
      const size_t ro = (size_t)(bid + k * 1024) * 512;
#pragma unroll
      for (int ct = 0; ct < 2; ++ct) {
        const int c0 = w * 32 + ct * 16 + quad * 4;
        ffp[kt][ct] = *(const uint2*)&os[ro + 128 + c0];
      }
    }
  }

  // GEMM: mfma(fb_frag, pw_frag) -> D.row = channel, D.col = k
  f32x4 acc[7][2];
#pragma unroll
  for (int kt = 0; kt < 7; ++kt)
#pragma unroll
    for (int ct = 0; ct < 2; ++ct) acc[kt][ct] = (f32x4){0.f, 0.f, 0.f, 0.f};
#pragma unroll
  for (int kj = 0; kj < 2; ++kj) {
    const int kk = kj * 32 + quad * 8;
    bf16x8 pa[7], fa[2];
#pragma unroll
    for (int kt = 0; kt < 7; ++kt)
      pa[kt] = *(const bf16x8*)&pwb[kt * 16 + lr][kk];
#pragma unroll
    for (int ct = 0; ct < 2; ++ct)
      fa[ct] = *(const bf16x8*)&fbuf[w * 32 + ct * 16 + lr][kk];
    __builtin_amdgcn_s_setprio(1);
#pragma unroll
    for (int kt = 0; kt < 7; ++kt)
#pragma unroll
      for (int ct = 0; ct < 2; ++ct)
        acc[kt][ct] = __builtin_amdgcn_mfma_f32_16x16x32_bf16(
            fa[ct], pa[kt], acc[kt][ct], 0, 0, 0);
    __builtin_amdgcn_s_setprio(0);
  }

  // fence: all feat_f/pw reads of this block complete before any row overwrite
  asm volatile("s_waitcnt vmcnt(0)" ::: "memory");
  __builtin_amdgcn_s_barrier();

  // epilogue: float4 stores; k = kt*16+lr, channels c0..c0+3
#pragma unroll
  for (int kt = 0; kt < 7; ++kt) {
    const int k = kt * 16 + lr;
    if (k < 100) {
      const size_t ro = (size_t)(bid + k * 1024) * 256;
#pragma unroll
      for (int ct = 0; ct < 2; ++ct) {
        const int c0 = w * 32 + ct * 16 + quad * 4;
        float4 v;
        v.x = acc[kt][ct][0];
        v.y = acc[kt][ct][1];
        v.z = acc[kt][ct][2];
        v.w = acc[kt][ct][3];
        *(float4*)(out_slot + ro + c0) = v;
        const uint2 ff = ffp[kt][ct];
        float4 f;
        f.x = v.x + bfbits2f(ff.x << 16);
        f.y = v.y + bfbits2f(ff.x & 0xffff0000u);
        f.z = v.z + bfbits2f(ff.y << 16);
        f.w = v.w + bfbits2f(ff.y & 0xffff0000u);
        *(float4*)(fused_slot + ro + c0) = f;
      }
    }
  }
}

extern "C" void kernel_launch(void* const* d_in, const int* in_sizes, int n_in,
                              void* d_out, int out_size, void* d_ws, size_t ws_size,
                              hipStream_t stream) {
  const float* feature = (const float*)d_in[0];
  const float* rois = (const float*)d_in[1];
  const float* Ww = (const float*)d_in[2];
  const float* bw = (const float*)d_in[3];
  const float* Wf = (const float*)d_in[4];
  const float* bfv = (const float*)d_in[5];
  const float* Wpw = (const float*)d_in[6];
  const float* bpw = (const float*)d_in[7];

  unsigned short* wsWf = (unsigned short*)d_ws;       // 65536 bf16 (frag-major)
  unsigned short* wsWw = wsWf + 256 * 256;            // 65536 bf16 (frag-major)
  unsigned short* wsWpw = wsWw + 256 * 256;           // 16384 bf16 (frag-major)

  float* fused_slot = (float*)d_out;
  float* out_slot = fused_slot + (size_t)MM * 256;

  k_convert<<<40, 256, 0, stream>>>(Wf, Ww, Wpw, wsWf, wsWw, wsWpw);
  k1<<<MM / 64, 256, 0, stream>>>(rois, wsWf, wsWw, wsWpw, bfv, bw, bpw,
                                  out_slot);
  k2<<<NN * FWBv * FWBv, 512, 0, stream>>>(feature, fused_slot, out_slot);
}

// Round 5
// 423.264 us; speedup vs baseline: 1.2007x; 1.0059x over previous
//
#include <hip/hip_runtime.h>

#define NN 4
#define CC 256
#define HH 128
#define FWBv 16
#define BLK 8
#define NBBOX 100
#define MM (NBBOX * NN * FWBv * FWBv)  // 102400

typedef __attribute__((ext_vector_type(8))) short bf16x8;
typedef __attribute__((ext_vector_type(4))) float f32x4;

__device__ __forceinline__ unsigned short f2bf(float x) {
  union { float f; unsigned int u; } v; v.f = x;
  unsigned int r = v.u + 0x7FFFu + ((v.u >> 16) & 1u);
  return (unsigned short)(r >> 16);
}

__device__ __forceinline__ float bfbits2f(unsigned int hi16) {
  union { float f; unsigned int u; } v; v.u = hi16;
  return v.f;
}

__device__ __forceinline__ unsigned int pk(float a, float b) {
  return (unsigned int)f2bf(a) | ((unsigned int)f2bf(b) << 16);
}

// ---------------- Kernel 0: weight fp32 -> bf16, FRAGMENT-MAJOR ----------------
// Wf/Ww: fragment f = (kc*16 + g)*64 + lane  (kc<8, g<16, lane<64)
//   holds W[g*16 + (lane&15)][kc*32 + (lane>>4)*8 + j], j=0..7  (16B per lane)
// Wpw:   fragment f = (kc*4 + g)*64 + lane   (kc<8, g<4)
__global__ __launch_bounds__(256) void k_convert(
    const float* __restrict__ Wf, const float* __restrict__ Ww,
    const float* __restrict__ Wpw,
    unsigned short* __restrict__ oWf, unsigned short* __restrict__ oWw,
    unsigned short* __restrict__ oWpw) {
  const int i = blockIdx.x * 256 + threadIdx.x;  // grid = 40 blocks -> i < 10240
  if (i < 8192) {
    const int lane = i & 63, g = (i >> 6) & 15, kc = i >> 10;
    const int row = g * 16 + (lane & 15);
    const int col0 = kc * 32 + (lane >> 4) * 8;
    {
      const float* s = Wf + (size_t)row * 256 + col0;
      const float4 a = *(const float4*)s, b = *(const float4*)(s + 4);
      *(uint4*)(oWf + (size_t)i * 8) =
          make_uint4(pk(a.x, a.y), pk(a.z, a.w), pk(b.x, b.y), pk(b.z, b.w));
    }
    {
      const float* s = Ww + (size_t)row * 256 + col0;
      const float4 a = *(const float4*)s, b = *(const float4*)(s + 4);
      *(uint4*)(oWw + (size_t)i * 8) =
          make_uint4(pk(a.x, a.y), pk(a.z, a.w), pk(b.x, b.y), pk(b.z, b.w));
    }
  } else {
    const int j = i - 8192;  // [0, 2048)
    const int lane = j & 63, g = (j >> 6) & 3, kc = j >> 8;
    const int row = g * 16 + (lane & 15);
    const int col0 = kc * 32 + (lane >> 4) * 8;
    const float* s = Wpw + (size_t)row * 256 + col0;
    const float4 a = *(const float4*)s, b = *(const float4*)(s + 4);
    *(uint4*)(oWpw + (size_t)j * 8) =
        make_uint4(pk(a.x, a.y), pk(a.z, a.w), pk(b.x, b.y), pk(b.z, b.w));
  }
}

// fragment load: one coalesced 1KB global_load_dwordx4 per wave
__device__ __forceinline__ bf16x8 ld_frag(const unsigned short* __restrict__ W,
                                          int frag, int lane) {
  return *(const bf16x8*)(W + (((size_t)frag * 64 + lane) << 3));
}

// One BK=32 compute step: weights already in regs; 4 ds_read (xs) + 16 MFMA.
__device__ __forceinline__ void bodyR(const bf16x8 aw[4],
                                      const unsigned short (*xsp)[264],
                                      int kcol, int lr, f32x4 acc[4][4]) {
  bf16x8 bx[4];
#pragma unroll
  for (int mt = 0; mt < 4; ++mt)
    bx[mt] = *(const bf16x8*)&xsp[mt * 16 + lr][kcol];
  __builtin_amdgcn_s_setprio(1);
#pragma unroll
  for (int mt = 0; mt < 4; ++mt)
#pragma unroll
    for (int nt = 0; nt < 4; ++nt)
      acc[mt][nt] = __builtin_amdgcn_mfma_f32_16x16x32_bf16(
          aw[nt], bx[mt], acc[mt][nt], 0, 0, 0);
  __builtin_amdgcn_s_setprio(0);
}

// ---------------- Kernel 1: feat_f, feat_w, point_weight ----------------
// (unchanged from R4)
__global__ __launch_bounds__(256, 3) void k1(
    const float* __restrict__ rois,
    const unsigned short* __restrict__ Wf,   // bf16 fragment-major [8192][8]
    const unsigned short* __restrict__ Ww,   // bf16 fragment-major [8192][8]
    const unsigned short* __restrict__ Wpw,  // bf16 fragment-major [2048][8]
    const float* __restrict__ bf_, const float* __restrict__ bw_,
    const float* __restrict__ bpw_,
    float* __restrict__ out_slot)
{
  __shared__ __align__(16) unsigned short xs[64][264];  // 33.8 KB, only LDS
  unsigned short* os = (unsigned short*)out_slot;
  const int t = threadIdx.x;
  const int lane = t & 63, w = t >> 6;
  const int lr = lane & 15, quad = lane >> 4;
  const int row_base = blockIdx.x * 64;
  const int w4 = w * 4;

  // preload pass-A chunk 0 weights (in flight during the X stage)
  bf16x8 aw[2][4];
#pragma unroll
  for (int nt = 0; nt < 4; ++nt) aw[0][nt] = ld_frag(Wf, w4 + nt, lane);

  // stage X: 64x256 fp32 -> bf16 LDS (coalesced float4 loads)
#pragma unroll
  for (int i = 0; i < 16; ++i) {
    const int elem = (i * 256 + t) * 4;
    const int r = elem >> 8, c = elem & 255;
    const float4 v = *(const float4*)(rois + (size_t)row_base * 256 + elem);
    *(uint2*)&xs[r][c] = make_uint2(pk(v.x, v.y), pk(v.z, v.w));
  }
  asm volatile("s_waitcnt lgkmcnt(0)" ::: "memory");
  __builtin_amdgcn_s_barrier();  // xs visible to all waves

  f32x4 acc[4][4];
#pragma unroll
  for (int mt = 0; mt < 4; ++mt)
#pragma unroll
    for (int nt = 0; nt < 4; ++nt) acc[mt][nt] = (f32x4){0.f, 0.f, 0.f, 0.f};

  // ---- pass A: feat_f = relu(x @ Wf^T + bf) ----
#pragma unroll
  for (int kc = 0; kc < 8; ++kc) {
    const unsigned short* nsrc = (kc < 7) ? Wf : Ww;  // tail prefetches pass B
    const int nkc = (kc < 7) ? kc + 1 : 0;
#pragma unroll
    for (int nt = 0; nt < 4; ++nt)
      aw[(kc + 1) & 1][nt] = ld_frag(nsrc, nkc * 16 + w4 + nt, lane);
    bodyR(aw[kc & 1], xs, kc * 32 + quad * 8, lr, acc);
  }

  // epilogue A: feat_f = relu(acc+bias) -> bf16 into out_slot bytes [256,768)
#pragma unroll
  for (int nt = 0; nt < 4; ++nt) {
    const int col0 = w * 64 + nt * 16 + quad * 4;
    const float4 b4 = *(const float4*)(bf_ + col0);
#pragma unroll
    for (int mt = 0; mt < 4; ++mt) {
      float v0 = acc[mt][nt][0] + b4.x; v0 = v0 > 0.f ? v0 : 0.f;
      float v1 = acc[mt][nt][1] + b4.y; v1 = v1 > 0.f ? v1 : 0.f;
      float v2 = acc[mt][nt][2] + b4.z; v2 = v2 > 0.f ? v2 : 0.f;
      float v3 = acc[mt][nt][3] + b4.w; v3 = v3 > 0.f ? v3 : 0.f;
      *(uint2*)&os[(size_t)(row_base + mt * 16 + lr) * 512 + 128 + col0] =
          make_uint2(pk(v0, v1), pk(v2, v3));
      acc[mt][nt] = (f32x4){0.f, 0.f, 0.f, 0.f};  // reset for pass B
    }
  }

  // ---- pass B: feat_w = relu(x @ Ww^T + bw) ----
#pragma unroll
  for (int kc = 0; kc < 8; ++kc) {
    if (kc < 7) {
#pragma unroll
      for (int nt = 0; nt < 4; ++nt)
        aw[(kc + 1) & 1][nt] = ld_frag(Ww, (kc + 1) * 16 + w4 + nt, lane);
    }
    bodyR(aw[kc & 1], xs, kc * 32 + quad * 8, lr, acc);
  }

  // prefetch ALL pass-C weights to regs (8KB/wave from L2, hides under epiB)
  bf16x8 apw[8];
#pragma unroll
  for (int idx = 0; idx < 8; ++idx)
    apw[idx] = ld_frag(Wpw, idx * 4 + w, lane);

  __builtin_amdgcn_s_barrier();  // ALL waves done reading xs (pass B)

  // epilogue B: feat_w = relu(acc + bias) -> bf16 back into xs
#pragma unroll
  for (int nt = 0; nt < 4; ++nt) {
    const int col0 = w * 64 + nt * 16 + quad * 4;
    const float4 b4 = *(const float4*)(bw_ + col0);
#pragma unroll
    for (int mt = 0; mt < 4; ++mt) {
      float v0 = acc[mt][nt][0] + b4.x; v0 = v0 > 0.f ? v0 : 0.f;
      float v1 = acc[mt][nt][1] + b4.y; v1 = v1 > 0.f ? v1 : 0.f;
      float v2 = acc[mt][nt][2] + b4.z; v2 = v2 > 0.f ? v2 : 0.f;
      float v3 = acc[mt][nt][3] + b4.w; v3 = v3 > 0.f ? v3 : 0.f;
      *(uint2*)&xs[mt * 16 + lr][col0] = make_uint2(pk(v0, v1), pk(v2, v3));
    }
  }
  asm volatile("s_waitcnt lgkmcnt(0)" ::: "memory");
  __builtin_amdgcn_s_barrier();  // new xs (feat_w) visible

  // ---- pass C: pw = feat_w @ Wpw^T + bpw, wave w -> cols [w*16, w*16+16) ----
  f32x4 acc2[4];
#pragma unroll
  for (int mt = 0; mt < 4; ++mt) acc2[mt] = (f32x4){0.f, 0.f, 0.f, 0.f};
#pragma unroll
  for (int idx = 0; idx < 8; ++idx) {  // idx = c*2+kt
    const int kcol = idx * 32 + quad * 8;
    __builtin_amdgcn_s_setprio(1);
#pragma unroll
    for (int mt = 0; mt < 4; ++mt) {
      const bf16x8 bx = *(const bf16x8*)&xs[mt * 16 + lr][kcol];
      acc2[mt] =
          __builtin_amdgcn_mfma_f32_16x16x32_bf16(apw[idx], bx, acc2[mt], 0, 0, 0);
    }
    __builtin_amdgcn_s_setprio(0);
  }
  // epilogue C: pw bf16 into out_slot bytes [0,128)
  {
    const int j0 = w * 16 + quad * 4;
    const float4 bj = *(const float4*)(bpw_ + j0);
#pragma unroll
    for (int mt = 0; mt < 4; ++mt) {
      const float v0 = acc2[mt][0] + bj.x, v1 = acc2[mt][1] + bj.y;
      const float v2 = acc2[mt][2] + bj.z, v3 = acc2[mt][3] + bj.w;
      *(uint2*)&os[(size_t)(row_base + mt * 16 + lr) * 512 + j0] =
          make_uint2(pk(v0, v1), pk(v2, v3));
    }
  }
}

// ---------------- Kernel 2: einsum + fused add ----------------
// grid = 1024 blocks, 512 threads (8 waves).
// R5: VGPR-pressure fix for 2 blocks/CU occupancy:
//  - __launch_bounds__(512, 4) caps VGPR at 128 (4 waves/SIMD = 2 blocks/CU;
//    LDS 2x53KB = 106KB fits).
//  - pa loaded in two halves inside the GEMM (peak regs: acc56+fa16+pa16≈90).
//  - ffp prefetch moved AFTER the GEMM (GEMM is ~150cyc, nothing lost);
//    fence order unchanged: issue ffp -> vmcnt(0) -> barrier -> stores.
__global__ __launch_bounds__(512, 4) void k2(
    const float* __restrict__ feature,
    float* __restrict__ fused_slot,
    float* __restrict__ out_slot)
{
  __shared__ unsigned short fbuf[256][72];  // fb[c][j] bf16
  __shared__ unsigned short pwb[112][72];   // pw[k][j] bf16, rows 100..111 zero
  const int t = threadIdx.x;
  const int lane = t & 63, w = t >> 6;
  const int lr = lane & 15, quad = lane >> 4;
  const int d = blockIdx.x;                 // hardware block id
  const int bid = ((d & 7) << 7) | (d >> 3);  // XCD-chunked logical id
  const int n = bid >> 8, p = (bid >> 4) & 15, q = bid & 15;
  const unsigned short* os = (const unsigned short*)out_slot;

  // zero pad rows k=100..111 (12 rows x 72 ushort = 432 uints)
  if (t < 432) {
    const int r = 100 + t / 36, cw = t % 36;
    *(unsigned int*)&pwb[r][cw * 2] = 0u;
  }

  // stage feature block: (c,a) pairs, 8 contiguous floats each
  for (int pi = t; pi < 2048; pi += 512) {
    const int c = pi >> 3, a = pi & 7;
    const float* fp =
        feature + (((size_t)n * 256 + c) * 128 + p * 8 + a) * 128 + q * 8;
    const float4 v0 = *(const float4*)fp;
    const float4 v1 = *(const float4*)(fp + 4);
    *(uint4*)&fbuf[c][a * 8] =
        make_uint4(pk(v0.x, v0.y), pk(v0.z, v0.w), pk(v1.x, v1.y), pk(v1.z, v1.w));
  }

  // stage pw rows (already bf16): k = 0..99, 128B per row
  for (int pi = t; pi < 1600; pi += 512) {
    const int k = pi >> 4, ch = pi & 15;
    const uint2 v = *(const uint2*)&os[(size_t)(bid + k * 1024) * 512 + ch * 4];
    *(uint2*)&pwb[k][ch * 4] = v;
  }
  __syncthreads();

  // GEMM: mfma(fb_frag, pw_frag) -> D.row = channel, D.col = k
  f32x4 acc[7][2];
#pragma unroll
  for (int kt = 0; kt < 7; ++kt)
#pragma unroll
    for (int ct = 0; ct < 2; ++ct) acc[kt][ct] = (f32x4){0.f, 0.f, 0.f, 0.f};
#pragma unroll
  for (int kj = 0; kj < 2; ++kj) {
    const int kk = kj * 32 + quad * 8;
    bf16x8 fa[2];
#pragma unroll
    for (int ct = 0; ct < 2; ++ct)
      fa[ct] = *(const bf16x8*)&fbuf[w * 32 + ct * 16 + lr][kk];
    {  // half 1: kt 0..3
      bf16x8 pa[4];
#pragma unroll
      for (int kt = 0; kt < 4; ++kt)
        pa[kt] = *(const bf16x8*)&pwb[kt * 16 + lr][kk];
      __builtin_amdgcn_s_setprio(1);
#pragma unroll
      for (int kt = 0; kt < 4; ++kt)
#pragma unroll
        for (int ct = 0; ct < 2; ++ct)
          acc[kt][ct] = __builtin_amdgcn_mfma_f32_16x16x32_bf16(
              fa[ct], pa[kt], acc[kt][ct], 0, 0, 0);
      __builtin_amdgcn_s_setprio(0);
    }
    {  // half 2: kt 4..6
      bf16x8 pa[3];
#pragma unroll
      for (int kt = 0; kt < 3; ++kt)
        pa[kt] = *(const bf16x8*)&pwb[(kt + 4) * 16 + lr][kk];
      __builtin_amdgcn_s_setprio(1);
#pragma unroll
      for (int kt = 0; kt < 3; ++kt)
#pragma unroll
        for (int ct = 0; ct < 2; ++ct)
          acc[kt + 4][ct] = __builtin_amdgcn_mfma_f32_16x16x32_bf16(
              fa[ct], pa[kt], acc[kt + 4][ct], 0, 0, 0);
      __builtin_amdgcn_s_setprio(0);
    }
  }

  // NOW issue feat_f bf16 prefetch (after GEMM: caps peak VGPR pressure)
  uint2 ffp[7][2];
#pragma unroll
  for (int kt = 0; kt < 7; ++kt) {
    const int k = kt * 16 + lr;
    if (k < 100) {
      const size_t ro = (size_t)(bid + k * 1024) * 512;
#pragma unroll
      for (int ct = 0; ct < 2; ++ct) {
        const int c0 = w * 32 + ct * 16 + quad * 4;
        ffp[kt][ct] = *(const uint2*)&os[ro + 128 + c0];
      }
    }
  }

  // fence: all feat_f/pw reads of this block complete before any row overwrite
  asm volatile("s_waitcnt vmcnt(0)" ::: "memory");
  __builtin_amdgcn_s_barrier();

  // epilogue: float4 stores; k = kt*16+lr, channels c0..c0+3
#pragma unroll
  for (int kt = 0; kt < 7; ++kt) {
    const int k = kt * 16 + lr;
    if (k < 100) {
      const size_t ro = (size_t)(bid + k * 1024) * 256;
#pragma unroll
      for (int ct = 0; ct < 2; ++ct) {
        const int c0 = w * 32 + ct * 16 + quad * 4;
        float4 v;
        v.x = acc[kt][ct][0];
        v.y = acc[kt][ct][1];
        v.z = acc[kt][ct][2];
        v.w = acc[kt][ct][3];
        *(float4*)(out_slot + ro + c0) = v;
        const uint2 ff = ffp[kt][ct];
        float4 f;
        f.x = v.x + bfbits2f(ff.x << 16);
        f.y = v.y + bfbits2f(ff.x & 0xffff0000u);
        f.z = v.z + bfbits2f(ff.y << 16);
        f.w = v.w + bfbits2f(ff.y & 0xffff0000u);
        *(float4*)(fused_slot + ro + c0) = f;
      }
    }
  }
}

extern "C" void kernel_launch(void* const* d_in, const int* in_sizes, int n_in,
                              void* d_out, int out_size, void* d_ws, size_t ws_size,
                              hipStream_t stream) {
  const float* feature = (const float*)d_in[0];
  const float* rois = (const float*)d_in[1];
  const float* Ww = (const float*)d_in[2];
  const float* bw = (const float*)d_in[3];
  const float* Wf = (const float*)d_in[4];
  const float* bfv = (const float*)d_in[5];
  const float* Wpw = (const float*)d_in[6];
  const float* bpw = (const float*)d_in[7];

  unsigned short* wsWf = (unsigned short*)d_ws;       // 65536 bf16 (frag-major)
  unsigned short* wsWw = wsWf + 256 * 256;            // 65536 bf16 (frag-major)
  unsigned short* wsWpw = wsWw + 256 * 256;           // 16384 bf16 (frag-major)

  float* fused_slot = (float*)d_out;
  float* out_slot = fused_slot + (size_t)MM * 256;

  k_convert<<<40, 256, 0, stream>>>(Wf, Ww, Wpw, wsWf, wsWw, wsWpw);
  k1<<<MM / 64, 256, 0, stream>>>(rois, wsWf, wsWw, wsWpw, bfv, bw, bpw,
                                  out_slot);
  k2<<<NN * FWBv * FWBv, 512, 0, stream>>>(feature, fused_slot, out_slot);
}